// Round 17
// baseline (151.843 us; speedup 1.0000x reference)
//
#include <hip/hip_runtime.h>
#include <hip/hip_bf16.h>

#define DIM 768
#define TD 2304
#define NB 8
#define NS 4096
#define NE 6

typedef __attribute__((ext_vector_type(8))) short bf16x8;
typedef __attribute__((ext_vector_type(4))) float f32x4;

// ws layout (float offsets)
#define OFF_BPK    0        // [72 ks][2 m][64 lane][8 j] u16 = 73728 u16 = 36864 f
#define OFF_A2F    36864    // [2304][6] f32 delta-mean fold
#define OFF_CB0    50688    // [16]
#define OFF_ACCSUM 50704    // [8][6] + pad = 64
#define OFF_CONSTB 50768    // [8][6] + pad = 64
#define OFF_QP4    50832    // [4 kq][32768][12] = 1572864

__device__ __forceinline__ unsigned short f2bf(float f) {
    union { float f; unsigned u; } a; a.f = f;
    unsigned r = a.u + 0x7FFFu + ((a.u >> 16) & 1u);
    return (unsigned short)(r >> 16);
}

__device__ __forceinline__ bf16x8 pack8(float4 a, float4 b) {
    union { bf16x8 v; __hip_bfloat162 h[4]; } u;
    u.h[0] = __float22bfloat162_rn(make_float2(a.x, a.y));
    u.h[1] = __float22bfloat162_rn(make_float2(a.z, a.w));
    u.h[2] = __float22bfloat162_rn(make_float2(b.x, b.y));
    u.h[3] = __float22bfloat162_rn(make_float2(b.z, b.w));
    return u.v;
}

// ---------------- kernel B: fold coefficients into MFMA B-fragment layout ----
__global__ __launch_bounds__(256) void k_fold(
    const float* __restrict__ Wspat, const float* __restrict__ Wtemp,
    const float* __restrict__ Wsync, const float* __restrict__ Wroute,
    const float* __restrict__ Wglob, const float* __restrict__ bglob,
    const float* __restrict__ broute, const float* __restrict__ bspat,
    const float* __restrict__ btemp, const float* __restrict__ bsync,
    unsigned short* __restrict__ Bpk, float* __restrict__ A2F,
    float* __restrict__ cb0, float* __restrict__ accsum)
{
    __shared__ float lwr[288 * NE];
    __shared__ float lgf[224 * NE];
    const int t = threadIdx.x;
    for (int i = t; i < 288 * NE; i += 256) lwr[i] = Wroute[i];
    __syncthreads();
    if (t < 224) {
        float g[NE] = {0, 0, 0, 0, 0, 0};
        for (int o = 0; o < 64; ++o) {
            const float w = Wglob[t * 64 + o];
            #pragma unroll
            for (int e = 0; e < NE; ++e) g[e] += w * lwr[(224 + o) * NE + e];
        }
        #pragma unroll
        for (int e = 0; e < NE; ++e) lgf[t * NE + e] = g[e];
    }
    __syncthreads();
    if (blockIdx.x == 0) {
        if (t < NE) {
            float a = broute[t];
            for (int o = 0; o < 64; ++o)  a += bglob[o] * lwr[(224 + o) * NE + t];
            for (int o = 0; o < 128; ++o) a += bspat[o] * (lwr[o * NE + t] + lgf[o * NE + t]);
            for (int o = 0; o < 64; ++o)  a += btemp[o] * (lwr[(128 + o) * NE + t] + lgf[(128 + o) * NE + t]);
            for (int o = 0; o < 32; ++o)  a += bsync[o] * (lwr[(192 + o) * NE + t] + lgf[(192 + o) * NE + t]);
            cb0[t] = a;
        }
        if (t >= 128 && t < 192) accsum[t - 128] = 0.f;
    }

    const int d = blockIdx.x * 256 + t;          // exactly 2304 threads
    const int st = d / DIM, dd = d - st * DIM;

    float p[NE] = {0, 0, 0, 0, 0, 0}, a2[NE] = {0, 0, 0, 0, 0, 0};
    for (int o = 0; o < 64; ++o) {
        const float w = Wtemp[d * 64 + o];
        #pragma unroll
        for (int e = 0; e < NE; ++e) {
            p[e]  += w * lwr[(128 + o) * NE + e];
            a2[e] += w * lgf[(128 + o) * NE + e];
        }
    }
    float qq[NE], a1[NE];
    #pragma unroll
    for (int e = 0; e < NE; ++e) { qq[e] = p[e]; a1[e] = 0.f; }
    for (int o = 0; o < 128; ++o) {
        const float w = Wspat[d * 128 + o];
        #pragma unroll
        for (int e = 0; e < NE; ++e) {
            qq[e] += w * lwr[o * NE + e];
            a1[e] += w * lgf[o * NE + e];
        }
    }
    if (st != 0) {
        const float sg = (st == 1) ? 1.f : -1.f;
        for (int o = 0; o < 32; ++o) {
            const float w = sg * Wsync[dd * 32 + o];
            #pragma unroll
            for (int e = 0; e < NE; ++e) {
                qq[e] += w * lwr[(192 + o) * NE + e];
                a1[e] += w * lgf[(192 + o) * NE + e];
            }
        }
    }
    // B-fragment scatter: B[k][n], k=d. frag: lane = (kk>>3)*16 + n, j = kk&7.
    const int ks = d >> 5, kk = d & 31;
    const int lh = (kk >> 3) * 16, j = kk & 7;
    unsigned short* b0 = Bpk + ks * 1024 + j;          // m=0 (Q/P outs 0-11)
    unsigned short* b1 = b0 + 512;                     // m=1 (A1 outs 0-5)
    #pragma unroll
    for (int e = 0; e < NE; ++e) {
        b0[(lh + e) * 8]     = f2bf(qq[e]);
        b0[(lh + 6 + e) * 8] = f2bf(p[e]);
        b1[(lh + e) * 8]     = f2bf(a1[e]);
        A2F[d * NE + e] = a2[e];
    }
}

// ---------------- kernel C: MFMA streaming GEMM, max-occupancy variant ----------------
// r16 body verbatim; geometry change only: K split into 4 quarters (9 chunks
// each) -> grid = 512 rowblocks * 4 kq = 2048 blocks = 8 blocks/CU; with
// VGPR<=64 (r16 measured 24) and LDS 0, launch_bounds(256,8) gives 32 waves/CU
// — ALL waves co-resident, 8 waves/SIMD interleaving load-stall windows.

#define GLOADX(A0, A1, A2, A3, C) { \
    const int gc_ = kq * 576 + (C) * 64; \
    const int st_ = gc_ / DIM; \
    const float* Xp_ = (st_ == 0) ? xt : ((st_ == 1) ? xa : xv); \
    const float* Xr_ = Xp_ + rowoff + (gc_ - st_ * DIM); \
    A0 = *(const float4*)(Xr_);      A1 = *(const float4*)(Xr_ + 4); \
    A2 = *(const float4*)(Xr_ + 32); A3 = *(const float4*)(Xr_ + 36); }

#define BLOAD(C, B00, B01, B10, B11) { \
    const unsigned short* bp = Bpk + ((kq * 9 + (C)) << 11) + (l << 3); \
    B00 = *(const bf16x8*)(bp); \
    B01 = *(const bf16x8*)(bp + 512); \
    B10 = *(const bf16x8*)(bp + 1024); \
    B11 = *(const bf16x8*)(bp + 1536); }

#define CMPT(A0, A1, A2, A3, B00, B01, B10, B11) { \
    const bf16x8 fA0 = pack8(A0, A1); \
    const bf16x8 fA1 = pack8(A2, A3); \
    acc0 = __builtin_amdgcn_mfma_f32_16x16x32_bf16(fA0, B00, acc0, 0, 0, 0); \
    acc1 = __builtin_amdgcn_mfma_f32_16x16x32_bf16(fA0, B01, acc1, 0, 0, 0); \
    acc0 = __builtin_amdgcn_mfma_f32_16x16x32_bf16(fA1, B10, acc0, 0, 0, 0); \
    acc1 = __builtin_amdgcn_mfma_f32_16x16x32_bf16(fA1, B11, acc1, 0, 0, 0); }

__global__ __launch_bounds__(256, 8) void k_main(
    const float* __restrict__ xt, const float* __restrict__ xa, const float* __restrict__ xv,
    const unsigned short* __restrict__ Bpk, float* __restrict__ accsum,
    float* __restrict__ qp4)
{
    const int t = threadIdx.x;
    const int l = t & 63;
    const int w = t >> 6;
    const int bid = blockIdx.x;
    const int kq = bid & 3;
    const int rblk = bid >> 2;
    const int rb0 = rblk << 6;
    const int bb = rblk >> 6;

    const int arow = rb0 + w * 16 + (l & 15);
    const size_t rowoff = (size_t)arow * DIM + (l >> 4) * 8;

    f32x4 acc0 = {0.f, 0.f, 0.f, 0.f};
    f32x4 acc1 = {0.f, 0.f, 0.f, 0.f};

    float4 pa0, pa1, pa2, pa3;
    bf16x8 Ba00, Ba01, Ba10, Ba11;

    #pragma unroll 1
    for (int c = 0; c < 9; ++c) {
        GLOADX(pa0, pa1, pa2, pa3, c)
        BLOAD(c, Ba00, Ba01, Ba10, Ba11)
        CMPT(pa0, pa1, pa2, pa3, Ba00, Ba01, Ba10, Ba11)
    }

    // epilogue: D layout col=lane&15, row=(lane>>4)*4+reg
    const int c_out = l & 15, rgrp = l >> 4;
    float* qph = qp4 + (size_t)kq * ((size_t)NB * NS * 12);
    if (c_out < 12) {
        const size_t rbase = (size_t)(rb0 + w * 16 + rgrp * 4) * 12 + c_out;
        qph[rbase]      = acc0[0];
        qph[rbase + 12] = acc0[1];
        qph[rbase + 24] = acc0[2];
        qph[rbase + 36] = acc0[3];
    }
    float v = acc1[0] + acc1[1] + acc1[2] + acc1[3];
    v += __shfl_xor(v, 16, 64);
    v += __shfl_xor(v, 32, 64);
    if (rgrp == 0 && c_out < 6)
        atomicAdd(&accsum[bb * NE + c_out], v);
}

// ---------------- kernel D: per-batch global constant ----------------
__global__ __launch_bounds__(256) void k_const(
    const float* __restrict__ xt, const float* __restrict__ xa, const float* __restrict__ xv,
    const float* __restrict__ accsum, const float* __restrict__ A2F,
    const float* __restrict__ cb0, float* __restrict__ constb)
{
    const int b = blockIdx.x, t = threadIdx.x;
    float acc[NE] = {0, 0, 0, 0, 0, 0};
    for (int f = t; f < TD; f += 256) {
        const int st = f / DIM, dd = f - st * DIM;
        const float* Xp = ((st == 0) ? xt : ((st == 1) ? xa : xv)) + (size_t)b * NS * DIM;
        const float dm = Xp[(size_t)(NS - 1) * DIM + dd] - Xp[dd];
        const float* Ap = A2F + f * NE;
        #pragma unroll
        for (int e = 0; e < NE; ++e) acc[e] += dm * Ap[e];
    }
    #pragma unroll
    for (int e = 0; e < NE; ++e)
        for (int m = 1; m < 64; m <<= 1) acc[e] += __shfl_xor(acc[e], m, 64);
    __shared__ float wred[4][NE];
    if ((t & 63) == 0) {
        #pragma unroll
        for (int e = 0; e < NE; ++e) wred[t >> 6][e] = acc[e];
    }
    __syncthreads();
    if (t < NE) {
        const float inv = 1.f / 4096.f;
        const float dsum = wred[0][t] + wred[1][t] + wred[2][t] + wred[3][t];
        constb[b * NE + t] = cb0[t] + accsum[b * NE + t] * inv + dsum * inv;
    }
}

// ---------------- kernel E: combine q - shifted p + const ----------------
__global__ __launch_bounds__(256) void k_add(
    const float* __restrict__ qp4, const float* __restrict__ constb, float* __restrict__ out)
{
    const int row = blockIdx.x * 256 + threadIdx.x;   // 32768 rows exact
    const int b = row >> 12, s = row & (NS - 1);
    const int rowp = (s == 0) ? row : row - 1;
    const size_t H = (size_t)NB * NS * 12;
    float o[NE];
    #pragma unroll
    for (int e = 0; e < NE; ++e) o[e] = constb[b * NE + e];
    #pragma unroll
    for (int kq = 0; kq < 4; ++kq) {
        const float* qr = qp4 + (size_t)kq * H + (size_t)row * 12;
        const float* pr = qp4 + (size_t)kq * H + (size_t)rowp * 12 + 6;
        #pragma unroll
        for (int e = 0; e < NE; ++e) o[e] += qr[e] - pr[e];
    }
    float* op = out + (size_t)row * NE;
    #pragma unroll
    for (int e = 0; e < NE; ++e) op[e] = o[e];
}

extern "C" void kernel_launch(void* const* d_in, const int* in_sizes, int n_in,
                              void* d_out, int out_size, void* d_ws, size_t ws_size,
                              hipStream_t stream)
{
    const float* xt     = (const float*)d_in[0];
    const float* xa     = (const float*)d_in[1];
    const float* xv     = (const float*)d_in[2];
    const float* Wspat  = (const float*)d_in[3];
    const float* bspat  = (const float*)d_in[4];
    const float* Wtemp  = (const float*)d_in[5];
    const float* btemp  = (const float*)d_in[6];
    const float* Wsync  = (const float*)d_in[7];
    const float* bsync  = (const float*)d_in[8];
    const float* Wglob  = (const float*)d_in[9];
    const float* bglob  = (const float*)d_in[10];
    const float* Wroute = (const float*)d_in[11];
    const float* broute = (const float*)d_in[12];
    float* out = (float*)d_out;

    float* ws = (float*)d_ws;
    unsigned short* Bpk = (unsigned short*)(ws + OFF_BPK);
    float* A2F    = ws + OFF_A2F;
    float* cb0    = ws + OFF_CB0;
    float* accsum = ws + OFF_ACCSUM;
    float* constb = ws + OFF_CONSTB;
    float* qp4    = ws + OFF_QP4;

    hipMemsetAsync(Bpk, 0, 73728 * sizeof(unsigned short), stream);
    k_fold<<<9, 256, 0, stream>>>(Wspat, Wtemp, Wsync, Wroute, Wglob, bglob,
                                  broute, bspat, btemp, bsync, Bpk, A2F, cb0, accsum);
    k_main<<<2048, 256, 0, stream>>>(xt, xa, xv, Bpk, accsum, qp4);
    k_const<<<8, 256, 0, stream>>>(xt, xa, xv, accsum, A2F, cb0, constb);
    k_add<<<128, 256, 0, stream>>>(qp4, constb, out);
}

// Round 18
// 116.389 us; speedup vs baseline: 1.3046x; 1.3046x over previous
//
#include <hip/hip_runtime.h>
#include <hip/hip_bf16.h>

#define DIM 768
#define TD 2304
#define NB 8
#define NS 4096
#define NE 6

typedef __attribute__((ext_vector_type(8))) short bf16x8;
typedef __attribute__((ext_vector_type(4))) float f32x4;

// ws layout (float offsets)
#define OFF_BPK    0        // [72 ks][2 m][64 lane][8 j] u16 = 73728 u16 = 36864 f
#define OFF_A2F    36864    // [2304][6] f32 delta-mean fold
#define OFF_CB0    50688    // [16]
#define OFF_ACCSUM 50704    // [8][6] + pad = 64
#define OFF_CONSTB 50768    // [8][6] + pad = 64
#define OFF_QP2    50832    // [2 khalf][32768][12] = 786432

__device__ __forceinline__ unsigned short f2bf(float f) {
    union { float f; unsigned u; } a; a.f = f;
    unsigned r = a.u + 0x7FFFu + ((a.u >> 16) & 1u);
    return (unsigned short)(r >> 16);
}

__device__ __forceinline__ bf16x8 pack8(float4 a, float4 b) {
    union { bf16x8 v; __hip_bfloat162 h[4]; } u;
    u.h[0] = __float22bfloat162_rn(make_float2(a.x, a.y));
    u.h[1] = __float22bfloat162_rn(make_float2(a.z, a.w));
    u.h[2] = __float22bfloat162_rn(make_float2(b.x, b.y));
    u.h[3] = __float22bfloat162_rn(make_float2(b.z, b.w));
    return u.v;
}

// ---------------- kernel B: fold coefficients into MFMA B-fragment layout ----
__global__ __launch_bounds__(256) void k_fold(
    const float* __restrict__ Wspat, const float* __restrict__ Wtemp,
    const float* __restrict__ Wsync, const float* __restrict__ Wroute,
    const float* __restrict__ Wglob, const float* __restrict__ bglob,
    const float* __restrict__ broute, const float* __restrict__ bspat,
    const float* __restrict__ btemp, const float* __restrict__ bsync,
    unsigned short* __restrict__ Bpk, float* __restrict__ A2F,
    float* __restrict__ cb0, float* __restrict__ accsum)
{
    __shared__ float lwr[288 * NE];
    __shared__ float lgf[224 * NE];
    const int t = threadIdx.x;
    for (int i = t; i < 288 * NE; i += 256) lwr[i] = Wroute[i];
    __syncthreads();
    if (t < 224) {
        float g[NE] = {0, 0, 0, 0, 0, 0};
        for (int o = 0; o < 64; ++o) {
            const float w = Wglob[t * 64 + o];
            #pragma unroll
            for (int e = 0; e < NE; ++e) g[e] += w * lwr[(224 + o) * NE + e];
        }
        #pragma unroll
        for (int e = 0; e < NE; ++e) lgf[t * NE + e] = g[e];
    }
    __syncthreads();
    if (blockIdx.x == 0) {
        if (t < NE) {
            float a = broute[t];
            for (int o = 0; o < 64; ++o)  a += bglob[o] * lwr[(224 + o) * NE + t];
            for (int o = 0; o < 128; ++o) a += bspat[o] * (lwr[o * NE + t] + lgf[o * NE + t]);
            for (int o = 0; o < 64; ++o)  a += btemp[o] * (lwr[(128 + o) * NE + t] + lgf[(128 + o) * NE + t]);
            for (int o = 0; o < 32; ++o)  a += bsync[o] * (lwr[(192 + o) * NE + t] + lgf[(192 + o) * NE + t]);
            cb0[t] = a;
        }
        if (t >= 128 && t < 192) accsum[t - 128] = 0.f;
    }

    const int d = blockIdx.x * 256 + t;          // exactly 2304 threads
    const int st = d / DIM, dd = d - st * DIM;

    float p[NE] = {0, 0, 0, 0, 0, 0}, a2[NE] = {0, 0, 0, 0, 0, 0};
    for (int o = 0; o < 64; ++o) {
        const float w = Wtemp[d * 64 + o];
        #pragma unroll
        for (int e = 0; e < NE; ++e) {
            p[e]  += w * lwr[(128 + o) * NE + e];
            a2[e] += w * lgf[(128 + o) * NE + e];
        }
    }
    float qq[NE], a1[NE];
    #pragma unroll
    for (int e = 0; e < NE; ++e) { qq[e] = p[e]; a1[e] = 0.f; }
    for (int o = 0; o < 128; ++o) {
        const float w = Wspat[d * 128 + o];
        #pragma unroll
        for (int e = 0; e < NE; ++e) {
            qq[e] += w * lwr[o * NE + e];
            a1[e] += w * lgf[o * NE + e];
        }
    }
    if (st != 0) {
        const float sg = (st == 1) ? 1.f : -1.f;
        for (int o = 0; o < 32; ++o) {
            const float w = sg * Wsync[dd * 32 + o];
            #pragma unroll
            for (int e = 0; e < NE; ++e) {
                qq[e] += w * lwr[(192 + o) * NE + e];
                a1[e] += w * lgf[(192 + o) * NE + e];
            }
        }
    }
    // B-fragment scatter: B[k][n], k=d. frag: lane = (kk>>3)*16 + n, j = kk&7.
    const int ks = d >> 5, kk = d & 31;
    const int lh = (kk >> 3) * 16, j = kk & 7;
    unsigned short* b0 = Bpk + ks * 1024 + j;          // m=0 (Q/P outs 0-11)
    unsigned short* b1 = b0 + 512;                     // m=1 (A1 outs 0-5)
    #pragma unroll
    for (int e = 0; e < NE; ++e) {
        b0[(lh + e) * 8]     = f2bf(qq[e]);
        b0[(lh + 6 + e) * 8] = f2bf(p[e]);
        b1[(lh + e) * 8]     = f2bf(a1[e]);
        A2F[d * NE + e] = a2[e];
    }
}

// ---------------- kernel C: MFMA streaming GEMM, B in LDS ----------------
// r16 structure; ONE change: the khalf's full B slab (72 KB) is staged into
// LDS once per block (18 coalesced float4 loads/thread + 1 barrier), then
// B-frags come from conflict-free ds_read_b128 on the DS pipe. Per-chunk
// VMEM drops 8 -> 4 instructions; B line-requests (half of all CU cache-line
// traffic, the measured ~5cy/line bottleneck) are eliminated.

#define GLOADX(A0, A1, A2, A3, C) { \
    const int gc_ = khalf * 1152 + (C) * 64; \
    const int st_ = gc_ / DIM; \
    const float* Xp_ = (st_ == 0) ? xt : ((st_ == 1) ? xa : xv); \
    const float* Xr_ = Xp_ + rowoff + (gc_ - st_ * DIM); \
    A0 = *(const float4*)(Xr_);      A1 = *(const float4*)(Xr_ + 4); \
    A2 = *(const float4*)(Xr_ + 32); A3 = *(const float4*)(Xr_ + 36); }

#define BLOADS(C, B00, B01, B10, B11) { \
    const unsigned short* bp = sB + ((C) << 11) + (l << 3); \
    B00 = *(const bf16x8*)(bp); \
    B01 = *(const bf16x8*)(bp + 512); \
    B10 = *(const bf16x8*)(bp + 1024); \
    B11 = *(const bf16x8*)(bp + 1536); }

#define CMPT(A0, A1, A2, A3, B00, B01, B10, B11) { \
    const bf16x8 fA0 = pack8(A0, A1); \
    const bf16x8 fA1 = pack8(A2, A3); \
    acc0 = __builtin_amdgcn_mfma_f32_16x16x32_bf16(fA0, B00, acc0, 0, 0, 0); \
    acc1 = __builtin_amdgcn_mfma_f32_16x16x32_bf16(fA0, B01, acc1, 0, 0, 0); \
    acc0 = __builtin_amdgcn_mfma_f32_16x16x32_bf16(fA1, B10, acc0, 0, 0, 0); \
    acc1 = __builtin_amdgcn_mfma_f32_16x16x32_bf16(fA1, B11, acc1, 0, 0, 0); }

__global__ __launch_bounds__(256, 2) void k_main(
    const float* __restrict__ xt, const float* __restrict__ xa, const float* __restrict__ xv,
    const unsigned short* __restrict__ Bpk, float* __restrict__ accsum,
    float* __restrict__ qp2)
{
    __shared__ unsigned short sB[36864];   // 72 KB: khalf's 18 chunks x 4 KB
    const int t = threadIdx.x;
    const int l = t & 63;
    const int w = t >> 6;
    const int bid = blockIdx.x;
    const int khalf = bid & 1;
    const int rblk = bid >> 1;
    const int rb0 = rblk << 6;
    const int bb = rblk >> 6;

    // stage B slab: 4608 float4 over 256 threads = 18 coalesced loads each
    {
        const float4* src = (const float4*)(Bpk + (size_t)khalf * 36864);
        float4* dst = (float4*)sB;
        #pragma unroll
        for (int i = 0; i < 18; ++i)
            dst[t + 256 * i] = src[t + 256 * i];
    }
    __syncthreads();

    const int arow = rb0 + w * 16 + (l & 15);
    const size_t rowoff = (size_t)arow * DIM + (l >> 4) * 8;

    f32x4 acc0 = {0.f, 0.f, 0.f, 0.f};
    f32x4 acc1 = {0.f, 0.f, 0.f, 0.f};

    float4 pa0, pa1, pa2, pa3;
    bf16x8 Ba00, Ba01, Ba10, Ba11;

    #pragma unroll 1
    for (int c = 0; c < 18; ++c) {
        GLOADX(pa0, pa1, pa2, pa3, c)
        BLOADS(c, Ba00, Ba01, Ba10, Ba11)
        CMPT(pa0, pa1, pa2, pa3, Ba00, Ba01, Ba10, Ba11)
    }

    // epilogue: D layout col=lane&15, row=(lane>>4)*4+reg
    const int c_out = l & 15, rgrp = l >> 4;
    float* qph = qp2 + (size_t)khalf * ((size_t)NB * NS * 12);
    if (c_out < 12) {
        const size_t rbase = (size_t)(rb0 + w * 16 + rgrp * 4) * 12 + c_out;
        qph[rbase]      = acc0[0];
        qph[rbase + 12] = acc0[1];
        qph[rbase + 24] = acc0[2];
        qph[rbase + 36] = acc0[3];
    }
    float v = acc1[0] + acc1[1] + acc1[2] + acc1[3];
    v += __shfl_xor(v, 16, 64);
    v += __shfl_xor(v, 32, 64);
    if (rgrp == 0 && c_out < 6)
        atomicAdd(&accsum[bb * NE + c_out], v);
}

// ---------------- kernel D: per-batch global constant ----------------
__global__ __launch_bounds__(256) void k_const(
    const float* __restrict__ xt, const float* __restrict__ xa, const float* __restrict__ xv,
    const float* __restrict__ accsum, const float* __restrict__ A2F,
    const float* __restrict__ cb0, float* __restrict__ constb)
{
    const int b = blockIdx.x, t = threadIdx.x;
    float acc[NE] = {0, 0, 0, 0, 0, 0};
    for (int f = t; f < TD; f += 256) {
        const int st = f / DIM, dd = f - st * DIM;
        const float* Xp = ((st == 0) ? xt : ((st == 1) ? xa : xv)) + (size_t)b * NS * DIM;
        const float dm = Xp[(size_t)(NS - 1) * DIM + dd] - Xp[dd];
        const float* Ap = A2F + f * NE;
        #pragma unroll
        for (int e = 0; e < NE; ++e) acc[e] += dm * Ap[e];
    }
    #pragma unroll
    for (int e = 0; e < NE; ++e)
        for (int m = 1; m < 64; m <<= 1) acc[e] += __shfl_xor(acc[e], m, 64);
    __shared__ float wred[4][NE];
    if ((t & 63) == 0) {
        #pragma unroll
        for (int e = 0; e < NE; ++e) wred[t >> 6][e] = acc[e];
    }
    __syncthreads();
    if (t < NE) {
        const float inv = 1.f / 4096.f;
        const float dsum = wred[0][t] + wred[1][t] + wred[2][t] + wred[3][t];
        constb[b * NE + t] = cb0[t] + accsum[b * NE + t] * inv + dsum * inv;
    }
}

// ---------------- kernel E: combine q - shifted p + const ----------------
__global__ __launch_bounds__(256) void k_add(
    const float* __restrict__ qp2, const float* __restrict__ constb, float* __restrict__ out)
{
    const int row = blockIdx.x * 256 + threadIdx.x;   // 32768 rows exact
    const int b = row >> 12, s = row & (NS - 1);
    const int rowp = (s == 0) ? row : row - 1;
    const size_t H = (size_t)NB * NS * 12;
    const float* q0 = qp2 + (size_t)row * 12;
    const float* q1 = qp2 + H + (size_t)row * 12;
    const float* p0 = qp2 + (size_t)rowp * 12 + 6;
    const float* p1 = qp2 + H + (size_t)rowp * 12 + 6;
    float* op = out + (size_t)row * NE;
    #pragma unroll
    for (int e = 0; e < NE; ++e)
        op[e] = constb[b * NE + e] + q0[e] + q1[e] - p0[e] - p1[e];
}

extern "C" void kernel_launch(void* const* d_in, const int* in_sizes, int n_in,
                              void* d_out, int out_size, void* d_ws, size_t ws_size,
                              hipStream_t stream)
{
    const float* xt     = (const float*)d_in[0];
    const float* xa     = (const float*)d_in[1];
    const float* xv     = (const float*)d_in[2];
    const float* Wspat  = (const float*)d_in[3];
    const float* bspat  = (const float*)d_in[4];
    const float* Wtemp  = (const float*)d_in[5];
    const float* btemp  = (const float*)d_in[6];
    const float* Wsync  = (const float*)d_in[7];
    const float* bsync  = (const float*)d_in[8];
    const float* Wglob  = (const float*)d_in[9];
    const float* bglob  = (const float*)d_in[10];
    const float* Wroute = (const float*)d_in[11];
    const float* broute = (const float*)d_in[12];
    float* out = (float*)d_out;

    float* ws = (float*)d_ws;
    unsigned short* Bpk = (unsigned short*)(ws + OFF_BPK);
    float* A2F    = ws + OFF_A2F;
    float* cb0    = ws + OFF_CB0;
    float* accsum = ws + OFF_ACCSUM;
    float* constb = ws + OFF_CONSTB;
    float* qp2    = ws + OFF_QP2;

    hipMemsetAsync(Bpk, 0, 73728 * sizeof(unsigned short), stream);
    k_fold<<<9, 256, 0, stream>>>(Wspat, Wtemp, Wsync, Wroute, Wglob, bglob,
                                  broute, bspat, btemp, bsync, Bpk, A2F, cb0, accsum);
    k_main<<<1024, 256, 0, stream>>>(xt, xa, xv, Bpk, accsum, qp2);
    k_const<<<8, 256, 0, stream>>>(xt, xa, xv, accsum, A2F, cb0, constb);
    k_add<<<128, 256, 0, stream>>>(qp2, constb, out);
}

// Round 19
// 115.492 us; speedup vs baseline: 1.3148x; 1.0078x over previous
//
#include <hip/hip_runtime.h>
#include <hip/hip_bf16.h>

#define DIM 768
#define TD 2304
#define NB 8
#define NS 4096
#define NE 6
#define LROW 772          // padded LDS row (float): bank-step 4 per row

typedef __attribute__((ext_vector_type(8))) short bf16x8;
typedef __attribute__((ext_vector_type(4))) float f32x4;

// ws layout (float offsets)
#define OFF_BPK    0        // [72 ks][2 m][64 lane][8 j] u16 = 36864 f
#define OFF_A2F    36864    // [2304][6] f32 delta-mean fold
#define OFF_CB0    50688    // [16]
#define OFF_ACCSUM 50704    // [8][6] + pad = 64
#define OFF_CONSTB 50768    // [8][6] + pad = 64
#define OFF_QP3    50832    // [3 st][32768][12] = 1179648

__device__ __forceinline__ unsigned short f2bf(float f) {
    union { float f; unsigned u; } a; a.f = f;
    unsigned r = a.u + 0x7FFFu + ((a.u >> 16) & 1u);
    return (unsigned short)(r >> 16);
}

__device__ __forceinline__ bf16x8 pack8(float4 a, float4 b) {
    union { bf16x8 v; __hip_bfloat162 h[4]; } u;
    u.h[0] = __float22bfloat162_rn(make_float2(a.x, a.y));
    u.h[1] = __float22bfloat162_rn(make_float2(a.z, a.w));
    u.h[2] = __float22bfloat162_rn(make_float2(b.x, b.y));
    u.h[3] = __float22bfloat162_rn(make_float2(b.z, b.w));
    return u.v;
}

// ---------------- kernel B: fold coefficients into MFMA B-fragment layout ----
__global__ __launch_bounds__(256) void k_fold(
    const float* __restrict__ Wspat, const float* __restrict__ Wtemp,
    const float* __restrict__ Wsync, const float* __restrict__ Wroute,
    const float* __restrict__ Wglob, const float* __restrict__ bglob,
    const float* __restrict__ broute, const float* __restrict__ bspat,
    const float* __restrict__ btemp, const float* __restrict__ bsync,
    unsigned short* __restrict__ Bpk, float* __restrict__ A2F,
    float* __restrict__ cb0, float* __restrict__ accsum)
{
    __shared__ float lwr[288 * NE];
    __shared__ float lgf[224 * NE];
    const int t = threadIdx.x;
    for (int i = t; i < 288 * NE; i += 256) lwr[i] = Wroute[i];
    __syncthreads();
    if (t < 224) {
        float g[NE] = {0, 0, 0, 0, 0, 0};
        for (int o = 0; o < 64; ++o) {
            const float w = Wglob[t * 64 + o];
            #pragma unroll
            for (int e = 0; e < NE; ++e) g[e] += w * lwr[(224 + o) * NE + e];
        }
        #pragma unroll
        for (int e = 0; e < NE; ++e) lgf[t * NE + e] = g[e];
    }
    __syncthreads();
    if (blockIdx.x == 0) {
        if (t < NE) {
            float a = broute[t];
            for (int o = 0; o < 64; ++o)  a += bglob[o] * lwr[(224 + o) * NE + t];
            for (int o = 0; o < 128; ++o) a += bspat[o] * (lwr[o * NE + t] + lgf[o * NE + t]);
            for (int o = 0; o < 64; ++o)  a += btemp[o] * (lwr[(128 + o) * NE + t] + lgf[(128 + o) * NE + t]);
            for (int o = 0; o < 32; ++o)  a += bsync[o] * (lwr[(192 + o) * NE + t] + lgf[(192 + o) * NE + t]);
            cb0[t] = a;
        }
        if (t >= 128 && t < 192) accsum[t - 128] = 0.f;
    }

    const int d = blockIdx.x * 256 + t;          // exactly 2304 threads
    const int st = d / DIM, dd = d - st * DIM;

    float p[NE] = {0, 0, 0, 0, 0, 0}, a2[NE] = {0, 0, 0, 0, 0, 0};
    for (int o = 0; o < 64; ++o) {
        const float w = Wtemp[d * 64 + o];
        #pragma unroll
        for (int e = 0; e < NE; ++e) {
            p[e]  += w * lwr[(128 + o) * NE + e];
            a2[e] += w * lgf[(128 + o) * NE + e];
        }
    }
    float qq[NE], a1[NE];
    #pragma unroll
    for (int e = 0; e < NE; ++e) { qq[e] = p[e]; a1[e] = 0.f; }
    for (int o = 0; o < 128; ++o) {
        const float w = Wspat[d * 128 + o];
        #pragma unroll
        for (int e = 0; e < NE; ++e) {
            qq[e] += w * lwr[o * NE + e];
            a1[e] += w * lgf[o * NE + e];
        }
    }
    if (st != 0) {
        const float sg = (st == 1) ? 1.f : -1.f;
        for (int o = 0; o < 32; ++o) {
            const float w = sg * Wsync[dd * 32 + o];
            #pragma unroll
            for (int e = 0; e < NE; ++e) {
                qq[e] += w * lwr[(192 + o) * NE + e];
                a1[e] += w * lgf[(192 + o) * NE + e];
            }
        }
    }
    // B-fragment scatter: B[k][n], k=d. frag: lane = (kk>>3)*16 + n, j = kk&7.
    const int ks = d >> 5, kk = d & 31;
    const int lh = (kk >> 3) * 16, j = kk & 7;
    unsigned short* b0 = Bpk + ks * 1024 + j;          // m=0 (Q/P outs 0-11)
    unsigned short* b1 = b0 + 512;                     // m=1 (A1 outs 0-5)
    #pragma unroll
    for (int e = 0; e < NE; ++e) {
        b0[(lh + e) * 8]     = f2bf(qq[e]);
        b0[(lh + 6 + e) * 8] = f2bf(p[e]);
        b1[(lh + e) * 8]     = f2bf(a1[e]);
        A2F[d * NE + e] = a2[e];
    }
}

// ---------------- kernel C: MFMA GEMM, m13-coalesced x ingestion ----------------
// grid = 3 streams * 512 rowblocks = 1536; block = 64 rows of ONE stream
// (contiguous 192 KB). 4 panels of 16 rows (48 KB flat contiguous). Staging:
// 12 float4/thread, 1 KB contiguous per wave-instruction (m13 pattern),
// T14-split (loads issued a full panel ahead, LDS write after barrier).
// All 4 waves compute the SAME 16 rows, splitting K 4-ways (3 chunks each);
// per-panel accs reduced through LDS once at the end.

#define LOADP(P) { \
    const float* s_ = xs + (size_t)(P) * 12288 + t * 4; \
    g0 = *(const float4*)(s_);          g1 = *(const float4*)(s_ + 1024); \
    g2 = *(const float4*)(s_ + 2048);   g3 = *(const float4*)(s_ + 3072); \
    g4 = *(const float4*)(s_ + 4096);   g5 = *(const float4*)(s_ + 5120); \
    g6 = *(const float4*)(s_ + 6144);   g7 = *(const float4*)(s_ + 7168); \
    g8 = *(const float4*)(s_ + 8192);   g9 = *(const float4*)(s_ + 9216); \
    g10 = *(const float4*)(s_ + 10240); g11 = *(const float4*)(s_ + 11264); }

#define WRITE1(GI, I) { \
    const int gg = (I) * 256 + t; \
    const int rr_ = gg / 192, gin_ = gg - rr_ * 192; \
    *(float4*)&sx[rr_ * LROW + gin_ * 4] = GI; }

#define WRITEP() { \
    WRITE1(g0, 0)  WRITE1(g1, 1)  WRITE1(g2, 2)  WRITE1(g3, 3) \
    WRITE1(g4, 4)  WRITE1(g5, 5)  WRITE1(g6, 6)  WRITE1(g7, 7) \
    WRITE1(g8, 8)  WRITE1(g9, 9)  WRITE1(g10, 10) WRITE1(g11, 11) }

#define CHUNK(CC, AC0, AC1) { \
    const float* ab_ = &sx[aoff + (CC) * 64]; \
    const float4 x0a = *(const float4*)(ab_); \
    const float4 x0b = *(const float4*)(ab_ + 4); \
    const float4 x1a = *(const float4*)(ab_ + 32); \
    const float4 x1b = *(const float4*)(ab_ + 36); \
    const unsigned short* bp = Bpk + ((size_t)(st * 12 + (CC)) << 11) + (l << 3); \
    const bf16x8 B00 = *(const bf16x8*)(bp); \
    const bf16x8 B01 = *(const bf16x8*)(bp + 512); \
    const bf16x8 B10 = *(const bf16x8*)(bp + 1024); \
    const bf16x8 B11 = *(const bf16x8*)(bp + 1536); \
    const bf16x8 fA0 = pack8(x0a, x0b); \
    const bf16x8 fA1 = pack8(x1a, x1b); \
    AC0 = __builtin_amdgcn_mfma_f32_16x16x32_bf16(fA0, B00, AC0, 0, 0, 0); \
    AC1 = __builtin_amdgcn_mfma_f32_16x16x32_bf16(fA0, B01, AC1, 0, 0, 0); \
    AC0 = __builtin_amdgcn_mfma_f32_16x16x32_bf16(fA1, B10, AC0, 0, 0, 0); \
    AC1 = __builtin_amdgcn_mfma_f32_16x16x32_bf16(fA1, B11, AC1, 0, 0, 0); }

#define PANEL(AC0, AC1) \
    CHUNK(3 * w + 0, AC0, AC1) \
    CHUNK(3 * w + 1, AC0, AC1) \
    CHUNK(3 * w + 2, AC0, AC1)

__global__ __launch_bounds__(256, 3) void k_main(
    const float* __restrict__ xt, const float* __restrict__ xa, const float* __restrict__ xv,
    const unsigned short* __restrict__ Bpk, float* __restrict__ accsum,
    float* __restrict__ qp3)
{
    __shared__ float sx[16 * LROW];   // 49.4 KB; reused for end-reduce
    const int t = threadIdx.x;
    const int l = t & 63;
    const int w = t >> 6;
    const int bid = blockIdx.x;
    const int st = bid / 512;
    const int rblk = bid - st * 512;
    const int row0 = rblk * 64;
    const int bb = rblk >> 6;

    const float* X = (st == 0) ? xt : ((st == 1) ? xa : xv);
    const float* xs = X + (size_t)row0 * DIM;

    const int rr = l & 15, h = l >> 4;
    const int aoff = rr * LROW + h * 8;

    f32x4 a00 = {0,0,0,0}, a01 = {0,0,0,0};   // panel 0: m0, m1
    f32x4 a10 = {0,0,0,0}, a11 = {0,0,0,0};
    f32x4 a20 = {0,0,0,0}, a21 = {0,0,0,0};
    f32x4 a30 = {0,0,0,0}, a31 = {0,0,0,0};

    float4 g0, g1, g2, g3, g4, g5, g6, g7, g8, g9, g10, g11;

    LOADP(0)
    WRITEP()
    __syncthreads();

    LOADP(1)                      // panel-1 loads in flight across panel-0 compute
    PANEL(a00, a01)
    __syncthreads();
    WRITEP()
    __syncthreads();

    LOADP(2)
    PANEL(a10, a11)
    __syncthreads();
    WRITEP()
    __syncthreads();

    LOADP(3)
    PANEL(a20, a21)
    __syncthreads();
    WRITEP()
    __syncthreads();

    PANEL(a30, a31)
    __syncthreads();

    // end-reduce: 4 panels x 4 waves x 64 lanes x 8 floats through sx
    {
        float* rp = &sx[0];
        #pragma unroll
        for (int p = 0; p < 4; ++p) {
            f32x4 c0 = (p == 0) ? a00 : (p == 1) ? a10 : (p == 2) ? a20 : a30;
            f32x4 c1 = (p == 0) ? a01 : (p == 1) ? a11 : (p == 2) ? a21 : a31;
            float* q = rp + ((p * 4 + w) * 64 + l) * 8;
            q[0] = c0[0]; q[1] = c0[1]; q[2] = c0[2]; q[3] = c0[3];
            q[4] = c1[0]; q[5] = c1[1]; q[6] = c1[2]; q[7] = c1[3];
        }
    }
    __syncthreads();
    {
        const int p = t >> 6;              // thread -> (panel, lane)
        const float* r0 = &sx[((p * 4 + 0) * 64 + l) * 8];
        const float* r1 = &sx[((p * 4 + 1) * 64 + l) * 8];
        const float* r2 = &sx[((p * 4 + 2) * 64 + l) * 8];
        const float* r3 = &sx[((p * 4 + 3) * 64 + l) * 8];
        float s0[4], s1[4];
        #pragma unroll
        for (int j = 0; j < 4; ++j) {
            s0[j] = r0[j] + r1[j] + r2[j] + r3[j];
            s1[j] = r0[4 + j] + r1[4 + j] + r2[4 + j] + r3[4 + j];
        }
        const int c_out = l & 15, rgrp = l >> 4;
        if (c_out < 12) {
            float* dst = qp3 + ((size_t)st * NB * NS + row0 + p * 16 + rgrp * 4) * 12 + c_out;
            dst[0]  = s0[0];
            dst[12] = s0[1];
            dst[24] = s0[2];
            dst[36] = s0[3];
        }
        float v = s1[0] + s1[1] + s1[2] + s1[3];
        v += __shfl_xor(v, 16, 64);
        v += __shfl_xor(v, 32, 64);
        if (rgrp == 0 && c_out < 6)
            atomicAdd(&accsum[bb * NE + c_out], v);
    }
}

// ---------------- kernel D: per-batch global constant ----------------
__global__ __launch_bounds__(256) void k_const(
    const float* __restrict__ xt, const float* __restrict__ xa, const float* __restrict__ xv,
    const float* __restrict__ accsum, const float* __restrict__ A2F,
    const float* __restrict__ cb0, float* __restrict__ constb)
{
    const int b = blockIdx.x, t = threadIdx.x;
    float acc[NE] = {0, 0, 0, 0, 0, 0};
    for (int f = t; f < TD; f += 256) {
        const int st = f / DIM, dd = f - st * DIM;
        const float* Xp = ((st == 0) ? xt : ((st == 1) ? xa : xv)) + (size_t)b * NS * DIM;
        const float dm = Xp[(size_t)(NS - 1) * DIM + dd] - Xp[dd];
        const float* Ap = A2F + f * NE;
        #pragma unroll
        for (int e = 0; e < NE; ++e) acc[e] += dm * Ap[e];
    }
    #pragma unroll
    for (int e = 0; e < NE; ++e)
        for (int m = 1; m < 64; m <<= 1) acc[e] += __shfl_xor(acc[e], m, 64);
    __shared__ float wred[4][NE];
    if ((t & 63) == 0) {
        #pragma unroll
        for (int e = 0; e < NE; ++e) wred[t >> 6][e] = acc[e];
    }
    __syncthreads();
    if (t < NE) {
        const float inv = 1.f / 4096.f;
        const float dsum = wred[0][t] + wred[1][t] + wred[2][t] + wred[3][t];
        constb[b * NE + t] = cb0[t] + accsum[b * NE + t] * inv + dsum * inv;
    }
}

// ---------------- kernel E: combine q - shifted p + const ----------------
__global__ __launch_bounds__(256) void k_add(
    const float* __restrict__ qp3, const float* __restrict__ constb, float* __restrict__ out)
{
    const int row = blockIdx.x * 256 + threadIdx.x;   // 32768 rows exact
    const int b = row >> 12, s = row & (NS - 1);
    const int rowp = (s == 0) ? row : row - 1;
    const size_t H = (size_t)NB * NS * 12;
    float o[NE];
    #pragma unroll
    for (int e = 0; e < NE; ++e) o[e] = constb[b * NE + e];
    #pragma unroll
    for (int st = 0; st < 3; ++st) {
        const float* qr = qp3 + (size_t)st * H + (size_t)row * 12;
        const float* pr = qp3 + (size_t)st * H + (size_t)rowp * 12 + 6;
        #pragma unroll
        for (int e = 0; e < NE; ++e) o[e] += qr[e] - pr[e];
    }
    float* op = out + (size_t)row * NE;
    #pragma unroll
    for (int e = 0; e < NE; ++e) op[e] = o[e];
}

extern "C" void kernel_launch(void* const* d_in, const int* in_sizes, int n_in,
                              void* d_out, int out_size, void* d_ws, size_t ws_size,
                              hipStream_t stream)
{
    const float* xt     = (const float*)d_in[0];
    const float* xa     = (const float*)d_in[1];
    const float* xv     = (const float*)d_in[2];
    const float* Wspat  = (const float*)d_in[3];
    const float* bspat  = (const float*)d_in[4];
    const float* Wtemp  = (const float*)d_in[5];
    const float* btemp  = (const float*)d_in[6];
    const float* Wsync  = (const float*)d_in[7];
    const float* bsync  = (const float*)d_in[8];
    const float* Wglob  = (const float*)d_in[9];
    const float* bglob  = (const float*)d_in[10];
    const float* Wroute = (const float*)d_in[11];
    const float* broute = (const float*)d_in[12];
    float* out = (float*)d_out;

    float* ws = (float*)d_ws;
    unsigned short* Bpk = (unsigned short*)(ws + OFF_BPK);
    float* A2F    = ws + OFF_A2F;
    float* cb0    = ws + OFF_CB0;
    float* accsum = ws + OFF_ACCSUM;
    float* constb = ws + OFF_CONSTB;
    float* qp3    = ws + OFF_QP3;

    hipMemsetAsync(Bpk, 0, 73728 * sizeof(unsigned short), stream);
    k_fold<<<9, 256, 0, stream>>>(Wspat, Wtemp, Wsync, Wroute, Wglob, bglob,
                                  broute, bspat, btemp, bsync, Bpk, A2F, cb0, accsum);
    k_main<<<1536, 256, 0, stream>>>(xt, xa, xv, Bpk, accsum, qp3);
    k_const<<<8, 256, 0, stream>>>(xt, xa, xv, accsum, A2F, cb0, constb);
    k_add<<<128, 256, 0, stream>>>(qp3, constb, out);
}

// Round 20
// 113.280 us; speedup vs baseline: 1.3404x; 1.0195x over previous
//
#include <hip/hip_runtime.h>
#include <hip/hip_bf16.h>

#define DIM 768
#define TD 2304
#define NB 8
#define NS 4096
#define NE 6
#define LROW 772          // padded LDS row (float): bank-step 4 per row

typedef __attribute__((ext_vector_type(8))) short bf16x8;
typedef __attribute__((ext_vector_type(4))) float f32x4;

// ws layout (float offsets)
#define OFF_BPK    0        // [72 ks][2 m][64 lane][8 j] u16 = 36864 f
#define OFF_A2F    36864    // [2304][6] f32 delta-mean fold
#define OFF_CB0    50688    // [16]
#define OFF_ACCSUM 50704    // [8][6] + pad = 64
#define OFF_CONSTB 50768    // [8][6] + pad = 64
#define OFF_QP3    50832    // [3 st][32768][12] = 1179648

__device__ __forceinline__ unsigned short f2bf(float f) {
    union { float f; unsigned u; } a; a.f = f;
    unsigned r = a.u + 0x7FFFu + ((a.u >> 16) & 1u);
    return (unsigned short)(r >> 16);
}

__device__ __forceinline__ bf16x8 pack8(float4 a, float4 b) {
    union { bf16x8 v; __hip_bfloat162 h[4]; } u;
    u.h[0] = __float22bfloat162_rn(make_float2(a.x, a.y));
    u.h[1] = __float22bfloat162_rn(make_float2(a.z, a.w));
    u.h[2] = __float22bfloat162_rn(make_float2(b.x, b.y));
    u.h[3] = __float22bfloat162_rn(make_float2(b.z, b.w));
    return u.v;
}

// ---------------- kernel B: fold coefficients into MFMA B-fragment layout ----
__global__ __launch_bounds__(256) void k_fold(
    const float* __restrict__ Wspat, const float* __restrict__ Wtemp,
    const float* __restrict__ Wsync, const float* __restrict__ Wroute,
    const float* __restrict__ Wglob, const float* __restrict__ bglob,
    const float* __restrict__ broute, const float* __restrict__ bspat,
    const float* __restrict__ btemp, const float* __restrict__ bsync,
    unsigned short* __restrict__ Bpk, float* __restrict__ A2F,
    float* __restrict__ cb0, float* __restrict__ accsum)
{
    __shared__ float lwr[288 * NE];
    __shared__ float lgf[224 * NE];
    const int t = threadIdx.x;
    for (int i = t; i < 288 * NE; i += 256) lwr[i] = Wroute[i];
    __syncthreads();
    if (t < 224) {
        float g[NE] = {0, 0, 0, 0, 0, 0};
        for (int o = 0; o < 64; ++o) {
            const float w = Wglob[t * 64 + o];
            #pragma unroll
            for (int e = 0; e < NE; ++e) g[e] += w * lwr[(224 + o) * NE + e];
        }
        #pragma unroll
        for (int e = 0; e < NE; ++e) lgf[t * NE + e] = g[e];
    }
    __syncthreads();
    if (blockIdx.x == 0) {
        if (t < NE) {
            float a = broute[t];
            for (int o = 0; o < 64; ++o)  a += bglob[o] * lwr[(224 + o) * NE + t];
            for (int o = 0; o < 128; ++o) a += bspat[o] * (lwr[o * NE + t] + lgf[o * NE + t]);
            for (int o = 0; o < 64; ++o)  a += btemp[o] * (lwr[(128 + o) * NE + t] + lgf[(128 + o) * NE + t]);
            for (int o = 0; o < 32; ++o)  a += bsync[o] * (lwr[(192 + o) * NE + t] + lgf[(192 + o) * NE + t]);
            cb0[t] = a;
        }
        if (t >= 128 && t < 192) accsum[t - 128] = 0.f;
    }

    const int d = blockIdx.x * 256 + t;          // exactly 2304 threads
    const int st = d / DIM, dd = d - st * DIM;

    float p[NE] = {0, 0, 0, 0, 0, 0}, a2[NE] = {0, 0, 0, 0, 0, 0};
    for (int o = 0; o < 64; ++o) {
        const float w = Wtemp[d * 64 + o];
        #pragma unroll
        for (int e = 0; e < NE; ++e) {
            p[e]  += w * lwr[(128 + o) * NE + e];
            a2[e] += w * lgf[(128 + o) * NE + e];
        }
    }
    float qq[NE], a1[NE];
    #pragma unroll
    for (int e = 0; e < NE; ++e) { qq[e] = p[e]; a1[e] = 0.f; }
    for (int o = 0; o < 128; ++o) {
        const float w = Wspat[d * 128 + o];
        #pragma unroll
        for (int e = 0; e < NE; ++e) {
            qq[e] += w * lwr[o * NE + e];
            a1[e] += w * lgf[o * NE + e];
        }
    }
    if (st != 0) {
        const float sg = (st == 1) ? 1.f : -1.f;
        for (int o = 0; o < 32; ++o) {
            const float w = sg * Wsync[dd * 32 + o];
            #pragma unroll
            for (int e = 0; e < NE; ++e) {
                qq[e] += w * lwr[(192 + o) * NE + e];
                a1[e] += w * lgf[(192 + o) * NE + e];
            }
        }
    }
    // B-fragment scatter: B[k][n], k=d. frag: lane = (kk>>3)*16 + n, j = kk&7.
    const int ks = d >> 5, kk = d & 31;
    const int lh = (kk >> 3) * 16, j = kk & 7;
    unsigned short* b0 = Bpk + ks * 1024 + j;          // m=0 (Q/P outs 0-11)
    unsigned short* b1 = b0 + 512;                     // m=1 (A1 outs 0-5)
    #pragma unroll
    for (int e = 0; e < NE; ++e) {
        b0[(lh + e) * 8]     = f2bf(qq[e]);
        b0[(lh + 6 + e) * 8] = f2bf(p[e]);
        b1[(lh + e) * 8]     = f2bf(a1[e]);
        A2F[d * NE + e] = a2[e];
    }
}

// ---------------- kernel C: MFMA GEMM, coalesced x + register-resident B ----------------
// r19 structure; ONE change: each wave's B working set (3 chunks x 4 bf16x8 =
// 48 VGPRs) is loaded ONCE before the panel loop and reused across all 4
// panels. Eliminates the B re-reads (295 MB of line traffic, half the total).
// Per-wave VMEM: 96 -> 60 instructions.

#define LOADP(P) { \
    const float* s_ = xs + (size_t)(P) * 12288 + t * 4; \
    g0 = *(const float4*)(s_);          g1 = *(const float4*)(s_ + 1024); \
    g2 = *(const float4*)(s_ + 2048);   g3 = *(const float4*)(s_ + 3072); \
    g4 = *(const float4*)(s_ + 4096);   g5 = *(const float4*)(s_ + 5120); \
    g6 = *(const float4*)(s_ + 6144);   g7 = *(const float4*)(s_ + 7168); \
    g8 = *(const float4*)(s_ + 8192);   g9 = *(const float4*)(s_ + 9216); \
    g10 = *(const float4*)(s_ + 10240); g11 = *(const float4*)(s_ + 11264); }

#define WRITE1(GI, I) { \
    const int gg = (I) * 256 + t; \
    const int rr_ = gg / 192, gin_ = gg - rr_ * 192; \
    *(float4*)&sx[rr_ * LROW + gin_ * 4] = GI; }

#define WRITEP() { \
    WRITE1(g0, 0)  WRITE1(g1, 1)  WRITE1(g2, 2)  WRITE1(g3, 3) \
    WRITE1(g4, 4)  WRITE1(g5, 5)  WRITE1(g6, 6)  WRITE1(g7, 7) \
    WRITE1(g8, 8)  WRITE1(g9, 9)  WRITE1(g10, 10) WRITE1(g11, 11) }

#define BLOADR(CC, B00, B01, B10, B11) { \
    const unsigned short* bp = Bpk + ((size_t)(st * 12 + (CC)) << 11) + (l << 3); \
    B00 = *(const bf16x8*)(bp); \
    B01 = *(const bf16x8*)(bp + 512); \
    B10 = *(const bf16x8*)(bp + 1024); \
    B11 = *(const bf16x8*)(bp + 1536); }

#define CHUNK(CC, B00, B01, B10, B11, AC0, AC1) { \
    const float* ab_ = &sx[aoff + (CC) * 64]; \
    const float4 x0a = *(const float4*)(ab_); \
    const float4 x0b = *(const float4*)(ab_ + 4); \
    const float4 x1a = *(const float4*)(ab_ + 32); \
    const float4 x1b = *(const float4*)(ab_ + 36); \
    const bf16x8 fA0 = pack8(x0a, x0b); \
    const bf16x8 fA1 = pack8(x1a, x1b); \
    AC0 = __builtin_amdgcn_mfma_f32_16x16x32_bf16(fA0, B00, AC0, 0, 0, 0); \
    AC1 = __builtin_amdgcn_mfma_f32_16x16x32_bf16(fA0, B01, AC1, 0, 0, 0); \
    AC0 = __builtin_amdgcn_mfma_f32_16x16x32_bf16(fA1, B10, AC0, 0, 0, 0); \
    AC1 = __builtin_amdgcn_mfma_f32_16x16x32_bf16(fA1, B11, AC1, 0, 0, 0); }

#define PANEL(AC0, AC1) \
    CHUNK(3 * w + 0, Bq00, Bq01, Bq02, Bq03, AC0, AC1) \
    CHUNK(3 * w + 1, Bq10, Bq11, Bq12, Bq13, AC0, AC1) \
    CHUNK(3 * w + 2, Bq20, Bq21, Bq22, Bq23, AC0, AC1)

__global__ __launch_bounds__(256, 3) void k_main(
    const float* __restrict__ xt, const float* __restrict__ xa, const float* __restrict__ xv,
    const unsigned short* __restrict__ Bpk, float* __restrict__ accsum,
    float* __restrict__ qp3)
{
    __shared__ float sx[16 * LROW];   // 49.4 KB; reused for end-reduce
    const int t = threadIdx.x;
    const int l = t & 63;
    const int w = t >> 6;
    const int bid = blockIdx.x;
    const int st = bid / 512;
    const int rblk = bid - st * 512;
    const int row0 = rblk * 64;
    const int bb = rblk >> 6;

    const float* X = (st == 0) ? xt : ((st == 1) ? xa : xv);
    const float* xs = X + (size_t)row0 * DIM;

    const int rr = l & 15, h = l >> 4;
    const int aoff = rr * LROW + h * 8;

    // register-resident B: this wave's 3 chunks, loaded ONCE
    bf16x8 Bq00, Bq01, Bq02, Bq03;
    bf16x8 Bq10, Bq11, Bq12, Bq13;
    bf16x8 Bq20, Bq21, Bq22, Bq23;
    BLOADR(3 * w + 0, Bq00, Bq01, Bq02, Bq03)
    BLOADR(3 * w + 1, Bq10, Bq11, Bq12, Bq13)
    BLOADR(3 * w + 2, Bq20, Bq21, Bq22, Bq23)

    f32x4 a00 = {0,0,0,0}, a01 = {0,0,0,0};   // panel accs: m0, m1
    f32x4 a10 = {0,0,0,0}, a11 = {0,0,0,0};
    f32x4 a20 = {0,0,0,0}, a21 = {0,0,0,0};
    f32x4 a30 = {0,0,0,0}, a31 = {0,0,0,0};

    float4 g0, g1, g2, g3, g4, g5, g6, g7, g8, g9, g10, g11;

    LOADP(0)
    WRITEP()
    __syncthreads();

    LOADP(1)                      // panel-1 loads in flight across panel-0 compute
    PANEL(a00, a01)
    __syncthreads();
    WRITEP()
    __syncthreads();

    LOADP(2)
    PANEL(a10, a11)
    __syncthreads();
    WRITEP()
    __syncthreads();

    LOADP(3)
    PANEL(a20, a21)
    __syncthreads();
    WRITEP()
    __syncthreads();

    PANEL(a30, a31)
    __syncthreads();

    // end-reduce: 4 panels x 4 waves x 64 lanes x 8 floats through sx
    {
        float* rp = &sx[0];
        #pragma unroll
        for (int p = 0; p < 4; ++p) {
            f32x4 c0 = (p == 0) ? a00 : (p == 1) ? a10 : (p == 2) ? a20 : a30;
            f32x4 c1 = (p == 0) ? a01 : (p == 1) ? a11 : (p == 2) ? a21 : a31;
            float* q = rp + ((p * 4 + w) * 64 + l) * 8;
            q[0] = c0[0]; q[1] = c0[1]; q[2] = c0[2]; q[3] = c0[3];
            q[4] = c1[0]; q[5] = c1[1]; q[6] = c1[2]; q[7] = c1[3];
        }
    }
    __syncthreads();
    {
        const int p = t >> 6;              // thread -> (panel, lane)
        const float* r0 = &sx[((p * 4 + 0) * 64 + l) * 8];
        const float* r1 = &sx[((p * 4 + 1) * 64 + l) * 8];
        const float* r2 = &sx[((p * 4 + 2) * 64 + l) * 8];
        const float* r3 = &sx[((p * 4 + 3) * 64 + l) * 8];
        float s0[4], s1[4];
        #pragma unroll
        for (int j = 0; j < 4; ++j) {
            s0[j] = r0[j] + r1[j] + r2[j] + r3[j];
            s1[j] = r0[4 + j] + r1[4 + j] + r2[4 + j] + r3[4 + j];
        }
        const int c_out = l & 15, rgrp = l >> 4;
        if (c_out < 12) {
            float* dst = qp3 + ((size_t)st * NB * NS + row0 + p * 16 + rgrp * 4) * 12 + c_out;
            dst[0]  = s0[0];
            dst[12] = s0[1];
            dst[24] = s0[2];
            dst[36] = s0[3];
        }
        float v = s1[0] + s1[1] + s1[2] + s1[3];
        v += __shfl_xor(v, 16, 64);
        v += __shfl_xor(v, 32, 64);
        if (rgrp == 0 && c_out < 6)
            atomicAdd(&accsum[bb * NE + c_out], v);
    }
}

// ---------------- kernel D: per-batch global constant ----------------
__global__ __launch_bounds__(256) void k_const(
    const float* __restrict__ xt, const float* __restrict__ xa, const float* __restrict__ xv,
    const float* __restrict__ accsum, const float* __restrict__ A2F,
    const float* __restrict__ cb0, float* __restrict__ constb)
{
    const int b = blockIdx.x, t = threadIdx.x;
    float acc[NE] = {0, 0, 0, 0, 0, 0};
    for (int f = t; f < TD; f += 256) {
        const int st = f / DIM, dd = f - st * DIM;
        const float* Xp = ((st == 0) ? xt : ((st == 1) ? xa : xv)) + (size_t)b * NS * DIM;
        const float dm = Xp[(size_t)(NS - 1) * DIM + dd] - Xp[dd];
        const float* Ap = A2F + f * NE;
        #pragma unroll
        for (int e = 0; e < NE; ++e) acc[e] += dm * Ap[e];
    }
    #pragma unroll
    for (int e = 0; e < NE; ++e)
        for (int m = 1; m < 64; m <<= 1) acc[e] += __shfl_xor(acc[e], m, 64);
    __shared__ float wred[4][NE];
    if ((t & 63) == 0) {
        #pragma unroll
        for (int e = 0; e < NE; ++e) wred[t >> 6][e] = acc[e];
    }
    __syncthreads();
    if (t < NE) {
        const float inv = 1.f / 4096.f;
        const float dsum = wred[0][t] + wred[1][t] + wred[2][t] + wred[3][t];
        constb[b * NE + t] = cb0[t] + accsum[b * NE + t] * inv + dsum * inv;
    }
}

// ---------------- kernel E: combine q - shifted p + const ----------------
__global__ __launch_bounds__(256) void k_add(
    const float* __restrict__ qp3, const float* __restrict__ constb, float* __restrict__ out)
{
    const int row = blockIdx.x * 256 + threadIdx.x;   // 32768 rows exact
    const int b = row >> 12, s = row & (NS - 1);
    const int rowp = (s == 0) ? row : row - 1;
    const size_t H = (size_t)NB * NS * 12;
    float o[NE];
    #pragma unroll
    for (int e = 0; e < NE; ++e) o[e] = constb[b * NE + e];
    #pragma unroll
    for (int st = 0; st < 3; ++st) {
        const float* qr = qp3 + (size_t)st * H + (size_t)row * 12;
        const float* pr = qp3 + (size_t)st * H + (size_t)rowp * 12 + 6;
        #pragma unroll
        for (int e = 0; e < NE; ++e) o[e] += qr[e] - pr[e];
    }
    float* op = out + (size_t)row * NE;
    #pragma unroll
    for (int e = 0; e < NE; ++e) op[e] = o[e];
}

extern "C" void kernel_launch(void* const* d_in, const int* in_sizes, int n_in,
                              void* d_out, int out_size, void* d_ws, size_t ws_size,
                              hipStream_t stream)
{
    const float* xt     = (const float*)d_in[0];
    const float* xa     = (const float*)d_in[1];
    const float* xv     = (const float*)d_in[2];
    const float* Wspat  = (const float*)d_in[3];
    const float* bspat  = (const float*)d_in[4];
    const float* Wtemp  = (const float*)d_in[5];
    const float* btemp  = (const float*)d_in[6];
    const float* Wsync  = (const float*)d_in[7];
    const float* bsync  = (const float*)d_in[8];
    const float* Wglob  = (const float*)d_in[9];
    const float* bglob  = (const float*)d_in[10];
    const float* Wroute = (const float*)d_in[11];
    const float* broute = (const float*)d_in[12];
    float* out = (float*)d_out;

    float* ws = (float*)d_ws;
    unsigned short* Bpk = (unsigned short*)(ws + OFF_BPK);
    float* A2F    = ws + OFF_A2F;
    float* cb0    = ws + OFF_CB0;
    float* accsum = ws + OFF_ACCSUM;
    float* constb = ws + OFF_CONSTB;
    float* qp3    = ws + OFF_QP3;

    hipMemsetAsync(Bpk, 0, 73728 * sizeof(unsigned short), stream);
    k_fold<<<9, 256, 0, stream>>>(Wspat, Wtemp, Wsync, Wroute, Wglob, bglob,
                                  broute, bspat, btemp, bsync, Bpk, A2F, cb0, accsum);
    k_main<<<1536, 256, 0, stream>>>(xt, xa, xv, Bpk, accsum, qp3);
    k_const<<<8, 256, 0, stream>>>(xt, xa, xv, accsum, A2F, cb0, constb);
    k_add<<<128, 256, 0, stream>>>(qp3, constb, out);
}